// Round 5
// baseline (346.751 us; speedup 1.0000x reference)
//
#include <hip/hip_runtime.h>
#include <math.h>
#include <stdint.h>

#define N_ROWS 4096
#define N_COLS 50257
#define SMOOTH 0.1f

typedef float f4_t __attribute__((ext_vector_type(4)));  // clang vector: OK for nontemporal builtin

// Process one float4 with a single group-max check (branch ~never taken on
// typical data; 4 exps are independent -> good ILP).
__device__ __forceinline__ void proc4(f4_t v, float& m, float& z, float& sx) {
    sx += (v.x + v.y) + (v.z + v.w);
    float g = fmaxf(fmaxf(v.x, v.y), fmaxf(v.z, v.w));
    if (g > m) {           // rare: rescale accumulated z to new max
        z *= __expf(m - g);
        m = g;
    }
    z += (__expf(v.x - m) + __expf(v.y - m)) + (__expf(v.z - m) + __expf(v.w - m));
}

__global__ __launch_bounds__(256) void fused_loss_kernel(const float* __restrict__ x,
                                                         const int* __restrict__ tgt,
                                                         float* __restrict__ row_loss,
                                                         unsigned int* __restrict__ ticket,
                                                         float* __restrict__ out) {
    const int row = blockIdx.x;
    const float* __restrict__ p = x + (long long)row * N_COLS;
    const int tid = (int)threadIdx.x;

    // Prefetch target logit early (hides HBM latency under the main loop).
    float xt = 0.0f;
    if (tid == 0) {
        int t = tgt[row];
        xt = p[t];
    }

    float m = -INFINITY;
    float z = 0.0f;
    float sx = 0.0f;

    // Alignment prologue: rows are only 4B-aligned (C*4 % 16 == 4).
    uintptr_t addr = (uintptr_t)p;
    int head = (int)(((16u - (addr & 15u)) & 15u) >> 2);  // 0..3 elements to 16B alignment
    if (tid < head) {
        float v = p[tid];
        sx += v;
        m = v;
        z = 1.0f;   // exp(v - v) = 1
    }

    const int body = (N_COLS - head) >> 2;                 // number of float4
    const f4_t* __restrict__ pv = (const f4_t*)(p + head);

    // Unrolled x4: issue all four nontemporal loads before processing (deep MLP:
    // 64 B/lane in flight).
    int j = tid;
    for (; j + 768 < body; j += 1024) {
        f4_t a = __builtin_nontemporal_load(&pv[j]);
        f4_t b = __builtin_nontemporal_load(&pv[j + 256]);
        f4_t c = __builtin_nontemporal_load(&pv[j + 512]);
        f4_t d = __builtin_nontemporal_load(&pv[j + 768]);
        proc4(a, m, z, sx);
        proc4(b, m, z, sx);
        proc4(c, m, z, sx);
        proc4(d, m, z, sx);
    }
    for (; j < body; j += 256) {
        f4_t a = __builtin_nontemporal_load(&pv[j]);
        proc4(a, m, z, sx);
    }

    // Scalar tail (<= 3 elements).
    const int tail_start = head + (body << 2);
    const int rem = N_COLS - tail_start;
    if (tid < rem) {
        float v = p[tail_start + tid];
        sx += v;
        if (v > m) { z *= __expf(m - v); m = v; }
        z += __expf(v - m);
    }

    // Wave-level reduce (64 lanes).
    #pragma unroll
    for (int off = 32; off > 0; off >>= 1) {
        float mo = __shfl_down(m, off);
        float zo = __shfl_down(z, off);
        float so = __shfl_down(sx, off);
        float M  = fmaxf(m, mo);
        z = z * __expf(m - M) + zo * __expf(mo - M);
        m = M;
        sx += so;
    }

    // Cross-wave reduce via LDS (4 waves for 256 threads).
    __shared__ float ms[4], zs[4], ss[4];
    __shared__ int is_last;
    const int wid  = tid >> 6;
    const int lane = tid & 63;
    if (lane == 0) { ms[wid] = m; zs[wid] = z; ss[wid] = sx; }
    __syncthreads();

    if (tid == 0) {
        #pragma unroll
        for (int w = 1; w < 4; ++w) {
            float mo = ms[w], zo = zs[w];
            float M  = fmaxf(m, mo);
            z = z * __expf(m - M) + zo * __expf(mo - M);
            m = M;
            sx += ss[w];
        }
        const float lse = m + __logf(z);                 // log-sum-exp of the row
        const float lp_t = xt - lse;                     // log_probs[row, t]
        const float sum_lp = sx - (float)N_COLS * lse;   // sum_j log_probs[row, j]
        const float offv = SMOOTH / (float)(N_COLS - 1);
        const float loss = -((1.0f - SMOOTH - offv) * lp_t + offv * sum_lp);
        row_loss[row] = loss;
        __threadfence();                                  // release: make store visible device-wide
        unsigned int t = atomicAdd(ticket, 1u);           // device-scope RMW
        is_last = (t == N_ROWS - 1);
    }
    __syncthreads();

    // The block that drew the last ticket reduces all row losses -> mean.
    if (is_last) {
        __threadfence();                                  // acquire: see other blocks' stores
        float s = 0.0f;
        for (int i = tid; i < N_ROWS; i += 256) s += row_loss[i];

        #pragma unroll
        for (int off = 32; off > 0; off >>= 1) s += __shfl_down(s, off);

        __shared__ float fs[4];
        if (lane == 0) fs[wid] = s;
        __syncthreads();
        if (tid == 0) {
            out[0] = (fs[0] + fs[1] + fs[2] + fs[3]) / (float)N_ROWS;
        }
    }
}

extern "C" void kernel_launch(void* const* d_in, const int* in_sizes, int n_in,
                              void* d_out, int out_size, void* d_ws, size_t ws_size,
                              hipStream_t stream) {
    const float* x   = (const float*)d_in[0];
    const int*   tgt = (const int*)d_in[1];
    float* out = (float*)d_out;
    float* ws  = (float*)d_ws;                       // [0..4095]: row losses
    unsigned int* ticket = (unsigned int*)(ws + N_ROWS);  // [4096]: ticket counter

    hipMemsetAsync(ticket, 0, sizeof(unsigned int), stream);  // graph-capturable memset node
    fused_loss_kernel<<<N_ROWS, 256, 0, stream>>>(x, tgt, ws, ticket, out);
}

// Round 6
// 153.983 us; speedup vs baseline: 2.2519x; 2.2519x over previous
//
#include <hip/hip_runtime.h>
#include <math.h>
#include <stdint.h>

#define N_ROWS 4096
#define N_COLS 50257
#define SMOOTH 0.1f

typedef float f4_t __attribute__((ext_vector_type(4)));  // clang vector: OK for nontemporal builtin

// Process one float4 with a single group-max check (branch ~never taken on
// typical data; 4 exps are independent -> good ILP).
__device__ __forceinline__ void proc4(f4_t v, float& m, float& z, float& sx) {
    sx += (v.x + v.y) + (v.z + v.w);
    float g = fmaxf(fmaxf(v.x, v.y), fmaxf(v.z, v.w));
    if (g > m) {           // rare: rescale accumulated z to new max
        z *= __expf(m - g);
        m = g;
    }
    z += (__expf(v.x - m) + __expf(v.y - m)) + (__expf(v.z - m) + __expf(v.w - m));
}

__global__ __launch_bounds__(256) void fused_loss_kernel(const float* __restrict__ x,
                                                         const int* __restrict__ tgt,
                                                         float* __restrict__ out) {
    const int row = blockIdx.x;
    const float* __restrict__ p = x + (long long)row * N_COLS;
    const int tid = (int)threadIdx.x;

    // Prefetch target logit early (hides HBM latency under the main loop).
    float xt = 0.0f;
    if (tid == 0) {
        int t = tgt[row];
        xt = p[t];
    }

    float m = -INFINITY;
    float z = 0.0f;
    float sx = 0.0f;

    // Alignment prologue: rows are only 4B-aligned (C*4 % 16 == 4).
    uintptr_t addr = (uintptr_t)p;
    int head = (int)(((16u - (addr & 15u)) & 15u) >> 2);  // 0..3 elements to 16B alignment
    if (tid < head) {
        float v = p[tid];
        sx += v;
        m = v;
        z = 1.0f;   // exp(v - v) = 1
    }

    const int body = (N_COLS - head) >> 2;                 // number of float4
    const f4_t* __restrict__ pv = (const f4_t*)(p + head);

    // Unrolled x4: issue all four nontemporal loads before processing (deep MLP:
    // 64 B/lane in flight).
    int j = tid;
    for (; j + 768 < body; j += 1024) {
        f4_t a = __builtin_nontemporal_load(&pv[j]);
        f4_t b = __builtin_nontemporal_load(&pv[j + 256]);
        f4_t c = __builtin_nontemporal_load(&pv[j + 512]);
        f4_t d = __builtin_nontemporal_load(&pv[j + 768]);
        proc4(a, m, z, sx);
        proc4(b, m, z, sx);
        proc4(c, m, z, sx);
        proc4(d, m, z, sx);
    }
    for (; j < body; j += 256) {
        f4_t a = __builtin_nontemporal_load(&pv[j]);
        proc4(a, m, z, sx);
    }

    // Scalar tail (<= 3 elements).
    const int tail_start = head + (body << 2);
    const int rem = N_COLS - tail_start;
    if (tid < rem) {
        float v = p[tail_start + tid];
        sx += v;
        if (v > m) { z *= __expf(m - v); m = v; }
        z += __expf(v - m);
    }

    // Wave-level reduce (64 lanes).
    #pragma unroll
    for (int off = 32; off > 0; off >>= 1) {
        float mo = __shfl_down(m, off);
        float zo = __shfl_down(z, off);
        float so = __shfl_down(sx, off);
        float M  = fmaxf(m, mo);
        z = z * __expf(m - M) + zo * __expf(mo - M);
        m = M;
        sx += so;
    }

    // Cross-wave reduce via LDS (4 waves for 256 threads).
    __shared__ float ms[4], zs[4], ss[4];
    const int wid  = tid >> 6;
    const int lane = tid & 63;
    if (lane == 0) { ms[wid] = m; zs[wid] = z; ss[wid] = sx; }
    __syncthreads();

    if (tid == 0) {
        #pragma unroll
        for (int w = 1; w < 4; ++w) {
            float mo = ms[w], zo = zs[w];
            float M  = fmaxf(m, mo);
            z = z * __expf(m - M) + zo * __expf(mo - M);
            m = M;
            sx += ss[w];
        }
        const float lse = m + __logf(z);                 // log-sum-exp of the row
        const float lp_t = xt - lse;                     // log_probs[row, t]
        const float sum_lp = sx - (float)N_COLS * lse;   // sum_j log_probs[row, j]
        const float offv = SMOOTH / (float)(N_COLS - 1);
        const float loss = -((1.0f - SMOOTH - offv) * lp_t + offv * sum_lp);
        // One device-scope float atomic per block (no fences, no cache writeback).
        atomicAdd(out, loss * (1.0f / (float)N_ROWS));
    }
}

extern "C" void kernel_launch(void* const* d_in, const int* in_sizes, int n_in,
                              void* d_out, int out_size, void* d_ws, size_t ws_size,
                              hipStream_t stream) {
    const float* x   = (const float*)d_in[0];
    const int*   tgt = (const int*)d_in[1];
    float* out = (float*)d_out;

    hipMemsetAsync(out, 0, sizeof(float), stream);  // zero the accumulator (graph-capturable node)
    fused_loss_kernel<<<N_ROWS, 256, 0, stream>>>(x, tgt, out);
}

// Round 7
// 134.975 us; speedup vs baseline: 2.5690x; 1.1408x over previous
//
#include <hip/hip_runtime.h>
#include <math.h>
#include <stdint.h>

#define N_ROWS 4096
#define N_COLS 50257
#define SMOOTH 0.1f

typedef float f4_t __attribute__((ext_vector_type(4)));  // clang vector: OK for nontemporal builtin

// Process one float4 with a single group-max check (branch ~never taken on
// typical data; 4 exps are independent -> good ILP).
__device__ __forceinline__ void proc4(f4_t v, float& m, float& z, float& sx) {
    sx += (v.x + v.y) + (v.z + v.w);
    float g = fmaxf(fmaxf(v.x, v.y), fmaxf(v.z, v.w));
    if (g > m) {           // rare: rescale accumulated z to new max
        z *= __expf(m - g);
        m = g;
    }
    z += (__expf(v.x - m) + __expf(v.y - m)) + (__expf(v.z - m) + __expf(v.w - m));
}

__global__ __launch_bounds__(256) void row_loss_kernel(const float* __restrict__ x,
                                                       const int* __restrict__ tgt,
                                                       float* __restrict__ row_loss) {
    const int row = blockIdx.x;
    const float* __restrict__ p = x + (long long)row * N_COLS;
    const int tid = (int)threadIdx.x;

    // Prefetch target logit early (hides HBM latency under the main loop).
    float xt = 0.0f;
    if (tid == 0) {
        int t = tgt[row];
        xt = p[t];
    }

    float m = -INFINITY;
    float z = 0.0f;
    float sx = 0.0f;

    // Alignment prologue: rows are only 4B-aligned (C*4 % 16 == 4).
    uintptr_t addr = (uintptr_t)p;
    int head = (int)(((16u - (addr & 15u)) & 15u) >> 2);  // 0..3 elements to 16B alignment
    if (tid < head) {
        float v = p[tid];
        sx += v;
        m = v;
        z = 1.0f;   // exp(v - v) = 1
    }

    const int body = (N_COLS - head) >> 2;                 // number of float4
    const f4_t* __restrict__ pv = (const f4_t*)(p + head);

    // Unrolled x4: issue all four nontemporal loads before processing (deep MLP:
    // 64 B/lane in flight).
    int j = tid;
    for (; j + 768 < body; j += 1024) {
        f4_t a = __builtin_nontemporal_load(&pv[j]);
        f4_t b = __builtin_nontemporal_load(&pv[j + 256]);
        f4_t c = __builtin_nontemporal_load(&pv[j + 512]);
        f4_t d = __builtin_nontemporal_load(&pv[j + 768]);
        proc4(a, m, z, sx);
        proc4(b, m, z, sx);
        proc4(c, m, z, sx);
        proc4(d, m, z, sx);
    }
    for (; j < body; j += 256) {
        f4_t a = __builtin_nontemporal_load(&pv[j]);
        proc4(a, m, z, sx);
    }

    // Scalar tail (<= 3 elements).
    const int tail_start = head + (body << 2);
    const int rem = N_COLS - tail_start;
    if (tid < rem) {
        float v = p[tail_start + tid];
        sx += v;
        if (v > m) { z *= __expf(m - v); m = v; }
        z += __expf(v - m);
    }

    // Wave-level reduce (64 lanes).
    #pragma unroll
    for (int off = 32; off > 0; off >>= 1) {
        float mo = __shfl_down(m, off);
        float zo = __shfl_down(z, off);
        float so = __shfl_down(sx, off);
        float M  = fmaxf(m, mo);
        z = z * __expf(m - M) + zo * __expf(mo - M);
        m = M;
        sx += so;
    }

    // Cross-wave reduce via LDS (4 waves for 256 threads).
    __shared__ float ms[4], zs[4], ss[4];
    const int wid  = tid >> 6;
    const int lane = tid & 63;
    if (lane == 0) { ms[wid] = m; zs[wid] = z; ss[wid] = sx; }
    __syncthreads();

    if (tid == 0) {
        #pragma unroll
        for (int w = 1; w < 4; ++w) {
            float mo = ms[w], zo = zs[w];
            float M  = fmaxf(m, mo);
            z = z * __expf(m - M) + zo * __expf(mo - M);
            m = M;
            sx += ss[w];
        }
        const float lse = m + __logf(z);                 // log-sum-exp of the row
        const float lp_t = xt - lse;                     // log_probs[row, t]
        const float sum_lp = sx - (float)N_COLS * lse;   // sum_j log_probs[row, j]
        const float offv = SMOOTH / (float)(N_COLS - 1);
        const float loss = -((1.0f - SMOOTH - offv) * lp_t + offv * sum_lp);
        row_loss[row] = loss;
    }
}

// Single-wave mean: 4096 floats = 1024 float4, 16 per lane.
__global__ __launch_bounds__(64) void mean_kernel(const float* __restrict__ row_loss,
                                                  float* __restrict__ out) {
    const int lane = (int)threadIdx.x;
    const f4_t* __restrict__ rv = (const f4_t*)row_loss;  // ws is 16B-aligned
    float s = 0.0f;
    #pragma unroll
    for (int i = 0; i < 16; ++i) {
        f4_t v = rv[lane + (i << 6)];
        s += (v.x + v.y) + (v.z + v.w);
    }
    #pragma unroll
    for (int off = 32; off > 0; off >>= 1) s += __shfl_down(s, off);
    if (lane == 0) out[0] = s * (1.0f / (float)N_ROWS);
}

extern "C" void kernel_launch(void* const* d_in, const int* in_sizes, int n_in,
                              void* d_out, int out_size, void* d_ws, size_t ws_size,
                              hipStream_t stream) {
    const float* x   = (const float*)d_in[0];
    const int*   tgt = (const int*)d_in[1];
    float* out = (float*)d_out;
    float* ws  = (float*)d_ws;   // 4096 row losses

    row_loss_kernel<<<N_ROWS, 256, 0, stream>>>(x, tgt, ws);
    mean_kernel<<<1, 64, 0, stream>>>(ws, out);
}